// Round 1
// baseline (2738.962 us; speedup 1.0000x reference)
//
#include <hip/hip_runtime.h>
#include <hip/hip_bf16.h>
#include <math.h>

typedef __attribute__((ext_vector_type(8))) short short8;
typedef __attribute__((ext_vector_type(4))) float floatx4;

#define SCALE_F 0.17677669529663689f  // 1/sqrt(32)

__device__ __forceinline__ float bf2f(__hip_bfloat16 v){ return __bfloat162float(v); }

// ---------------- weight cast + transpose: src fp32 (K x N) -> dst bf16 (N x K) ----------------
__global__ void wcast_t(const float* __restrict__ src, __hip_bfloat16* __restrict__ dst, int K, int N)
{
    int idx = blockIdx.x * 256 + threadIdx.x;
    if (idx >= K * N) return;
    int n = idx / K, k = idx - n * K;
    dst[idx] = __float2bfloat16(src[(size_t)k * N + n]);
}

// ---------------- LayerNorm (+ optional shift + window partition) -> bf16 rows ----------------
// windowed=1: output row wr is window-ordered (win = bl*64 + wh*8 + ww, t = i*7+j),
//             source token = (b0+bl, (wh*7+i+shift)%56, (ww*7+j+shift)%56)
// windowed=0: output row wr corresponds to token b0*3136 + wr directly.
__global__ __launch_bounds__(256)
void ln_kernel(const float* __restrict__ x, const float* __restrict__ g,
               const float* __restrict__ bb, __hip_bfloat16* __restrict__ out,
               int b0, int shift, int windowed)
{
    int wave = threadIdx.x >> 6, lane = threadIdx.x & 63;
    int wr = blockIdx.x * 4 + wave;
    size_t src;
    if (windowed) {
        int win = wr / 49, t = wr - win * 49;
        int bl = win >> 6, wrem = win & 63;
        int wh = wrem >> 3, ww = wrem & 7;
        int i = t / 7, j = t - i * 7;
        int hh = wh * 7 + i + shift; if (hh >= 56) hh -= 56;
        int wp = ww * 7 + j + shift; if (wp >= 56) wp -= 56;
        src = (size_t)(b0 + bl) * 3136 + hh * 56 + wp;
    } else {
        src = (size_t)b0 * 3136 + wr;
    }
    const float* xr = x + src * 192;
    float v0 = xr[lane], v1 = xr[lane + 64], v2 = xr[lane + 128];
    float s = v0 + v1 + v2, ss = v0 * v0 + v1 * v1 + v2 * v2;
    #pragma unroll
    for (int o = 32; o; o >>= 1) { s += __shfl_xor(s, o); ss += __shfl_xor(ss, o); }
    float mu = s * (1.f / 192.f);
    float rs = rsqrtf(ss * (1.f / 192.f) - mu * mu + 1e-5f);
    __hip_bfloat16* op = out + (size_t)wr * 192;
    op[lane]       = __float2bfloat16((v0 - mu) * rs * g[lane]       + bb[lane]);
    op[lane + 64]  = __float2bfloat16((v1 - mu) * rs * g[lane + 64]  + bb[lane + 64]);
    op[lane + 128] = __float2bfloat16((v2 - mu) * rs * g[lane + 128] + bb[lane + 128]);
}

// ---------------- attention: one wave per (window, head) ----------------
// qkv: (nwin*49, 576) bf16 rows, col = which*192 + head*32 + d
// out: (nwin*49, 192) bf16, col = head*32 + d
__global__ __launch_bounds__(64)
void attn_kernel(const __hip_bfloat16* __restrict__ qkv, const float* __restrict__ rpb,
                 __hip_bfloat16* __restrict__ out, int shift)
{
    __shared__ float kx[49 * 32];
    __shared__ float vx[49 * 32];
    __shared__ float smv[49 * 49];
    __shared__ float rp[169];
    int win = blockIdx.x, head = blockIdx.y;
    int lane = threadIdx.x;
    const __hip_bfloat16* base = qkv + (size_t)win * 49 * 576;
    for (int idx = lane; idx < 49 * 32; idx += 64) {
        int t = idx >> 5, dd = idx & 31;
        kx[idx] = bf2f(base[t * 576 + 192 + head * 32 + dd]);
        vx[idx] = bf2f(base[t * 576 + 384 + head * 32 + dd]);
    }
    for (int idx = lane; idx < 169; idx += 64) rp[idx] = rpb[idx * 6 + head];
    __syncthreads();
    if (lane >= 49) return;
    const int r = lane;
    float q[32];
    #pragma unroll
    for (int dd = 0; dd < 32; ++dd)
        q[dd] = bf2f(base[r * 576 + head * 32 + dd]) * SCALE_F;
    int ri = r / 7, rj = r - ri * 7;
    int wrem = win & 63, wh = wrem >> 3, ww = wrem & 7;
    int hr = wh * 7 + ri, wrr = ww * 7 + rj;
    int idr = (hr < 49 ? 0 : (hr < 53 ? 1 : 2)) * 3 + (wrr < 49 ? 0 : (wrr < 53 ? 1 : 2));
    float mx = -1e30f;
    for (int m = 0; m < 49; ++m) {
        float acc = 0.f;
        #pragma unroll
        for (int dd = 0; dd < 32; ++dd) acc += q[dd] * kx[m * 32 + dd];
        int mi2 = m / 7, mj = m - mi2 * 7;
        acc += rp[(ri - mi2 + 6) * 13 + (rj - mj + 6)];
        if (shift > 0) {
            int hm = wh * 7 + mi2, wm = ww * 7 + mj;
            int idm = (hm < 49 ? 0 : (hm < 53 ? 1 : 2)) * 3 + (wm < 49 ? 0 : (wm < 53 ? 1 : 2));
            if (idm != idr) acc -= 100.f;
        }
        smv[r * 49 + m] = acc;
        mx = fmaxf(mx, acc);
    }
    float sum = 0.f;
    for (int m = 0; m < 49; ++m) { float e = __expf(smv[r * 49 + m] - mx); smv[r * 49 + m] = e; sum += e; }
    float inv = 1.f / sum;
    float o[32];
    #pragma unroll
    for (int dd = 0; dd < 32; ++dd) o[dd] = 0.f;
    for (int m = 0; m < 49; ++m) {
        float p = smv[r * 49 + m] * inv;
        #pragma unroll
        for (int dd = 0; dd < 32; ++dd) o[dd] += p * vx[m * 32 + dd];
    }
    __hip_bfloat16* op = out + ((size_t)win * 49 + r) * 192 + head * 32;
    #pragma unroll
    for (int dd = 0; dd < 32; ++dd) op[dd] = __float2bfloat16(o[dd]);
}

// ---------------- GEMM: C = A(M x K, bf16 row-major) @ Wt(N x K, bf16 row-major)^T + bias ----------------
// block tile 64x64, 4 waves (each wave: 16 rows x 64 cols), MFMA 16x16x32 bf16
// EPI 0: bias, store bf16 row-major (ld)
// EPI 1: bias + exact GELU, store bf16 row-major (ld)
// EPI 2: bias + window-reverse/roll scatter + residual add -> fp32
// EPI 3: bias + residual add (flat token order, offset b0*3136) -> fp32
struct EpiParams {
    float* out_f32;
    const float* resid;
    __hip_bfloat16* out_bf;
    int b0;
    int shift;
    int ld;
};

template<int EPI>
__global__ __launch_bounds__(256)
void gemm_bf16(const __hip_bfloat16* __restrict__ A,
               const __hip_bfloat16* __restrict__ Wt,
               const float* __restrict__ bias,
               int K, EpiParams ep)
{
    __shared__ __align__(16) __hip_bfloat16 As[64 * 32];
    __shared__ __align__(16) __hip_bfloat16 Bs[64 * 32];
    const int tid = threadIdx.x;
    const int row0 = blockIdx.x * 64;
    const int col0 = blockIdx.y * 64;
    const int wave = tid >> 6, lane = tid & 63;
    const int quad = lane >> 4, lr = lane & 15;
    floatx4 acc0 = {0.f, 0.f, 0.f, 0.f}, acc1 = acc0, acc2 = acc0, acc3 = acc0;
    const int sr = tid >> 2;
    const int sk = (tid & 3) << 3;
    const __hip_bfloat16* Ag = A + (size_t)(row0 + sr) * K + sk;
    const __hip_bfloat16* Bg = Wt + (size_t)(col0 + sr) * K + sk;
    for (int k0 = 0; k0 < K; k0 += 32) {
        uint4 av = *(const uint4*)(Ag + k0);
        uint4 bv = *(const uint4*)(Bg + k0);
        __syncthreads();
        *(uint4*)(As + sr * 32 + sk) = av;
        *(uint4*)(Bs + sr * 32 + sk) = bv;
        __syncthreads();
        short8 af  = *(const short8*)(As + (wave * 16 + lr) * 32 + quad * 8);
        short8 b0f = *(const short8*)(Bs + (lr) * 32 + quad * 8);
        short8 b1f = *(const short8*)(Bs + (16 + lr) * 32 + quad * 8);
        short8 b2f = *(const short8*)(Bs + (32 + lr) * 32 + quad * 8);
        short8 b3f = *(const short8*)(Bs + (48 + lr) * 32 + quad * 8);
        acc0 = __builtin_amdgcn_mfma_f32_16x16x32_bf16(af, b0f, acc0, 0, 0, 0);
        acc1 = __builtin_amdgcn_mfma_f32_16x16x32_bf16(af, b1f, acc1, 0, 0, 0);
        acc2 = __builtin_amdgcn_mfma_f32_16x16x32_bf16(af, b2f, acc2, 0, 0, 0);
        acc3 = __builtin_amdgcn_mfma_f32_16x16x32_bf16(af, b3f, acc3, 0, 0, 0);
    }
    floatx4 accs[4] = {acc0, acc1, acc2, acc3};
    #pragma unroll
    for (int c = 0; c < 4; ++c) {
        int col = col0 + c * 16 + lr;
        float bz = bias[col];
        #pragma unroll
        for (int rr = 0; rr < 4; ++rr) {
            int row = row0 + wave * 16 + quad * 4 + rr;
            float v = accs[c][rr] + bz;
            if constexpr (EPI == 0) {
                ep.out_bf[(size_t)row * ep.ld + col] = __float2bfloat16(v);
            } else if constexpr (EPI == 1) {
                float gl = 0.5f * v * (1.f + erff(v * 0.70710678118654752f));
                ep.out_bf[(size_t)row * ep.ld + col] = __float2bfloat16(gl);
            } else if constexpr (EPI == 2) {
                int win = row / 49, t = row - win * 49;
                int bl = win >> 6, wrem = win & 63;
                int wh = wrem >> 3, ww = wrem & 7;
                int i = t / 7, j = t - i * 7;
                int hh = wh * 7 + i + ep.shift; if (hh >= 56) hh -= 56;
                int wp = ww * 7 + j + ep.shift; if (wp >= 56) wp -= 56;
                size_t tok = (size_t)(ep.b0 + bl) * 3136 + hh * 56 + wp;
                size_t o = tok * 192 + col;
                ep.out_f32[o] = ep.resid[o] + v;
            } else { // EPI == 3
                size_t tok = (size_t)ep.b0 * 3136 + row;
                size_t o = tok * 192 + col;
                ep.out_f32[o] = ep.resid[o] + v;
            }
        }
    }
}

extern "C" void kernel_launch(void* const* d_in, const int* in_sizes, int n_in,
                              void* d_out, int out_size, void* d_ws, size_t ws_size,
                              hipStream_t stream)
{
    const float* x      = (const float*)d_in[0];
    const float* ln1_g  = (const float*)d_in[1];
    const float* ln1_b  = (const float*)d_in[2];
    const float* qkv_w  = (const float*)d_in[3];
    const float* qkv_b  = (const float*)d_in[4];
    const float* rpb    = (const float*)d_in[5];
    const float* proj_w = (const float*)d_in[6];
    const float* proj_b = (const float*)d_in[7];
    const float* ln2_g  = (const float*)d_in[8];
    const float* ln2_b  = (const float*)d_in[9];
    const float* fc1_w  = (const float*)d_in[10];
    const float* fc1_b  = (const float*)d_in[11];
    const float* fc2_w  = (const float*)d_in[12];
    const float* fc2_b  = (const float*)d_in[13];

    char* ws = (char*)d_ws;
    const size_t RN = 200704ull; // total tokens = 64*3136

    // choose batch-image chunk CB so everything fits in ws
    int CB = 64;
    auto need = [&](int cb) -> size_t {
        return RN * 192 * 4                      // fp32 residual stream
             + (size_t)cb * 3136 * 192 * 2       // bufA (LN out / attn out)
             + (size_t)cb * 3136 * 768 * 2       // bufB (qkv / MLP hidden)
             + 884736ull * 2 + 4096;             // bf16 transposed weights
    };
    while (CB > 1 && need(CB) > ws_size) CB >>= 1;

    float* R = (float*)ws;
    size_t off = RN * 192 * 4;
    __hip_bfloat16* bufA = (__hip_bfloat16*)(ws + off); off += (size_t)CB * 3136 * 192 * 2;
    __hip_bfloat16* bufB = (__hip_bfloat16*)(ws + off); off += (size_t)CB * 3136 * 768 * 2;
    __hip_bfloat16* wreg = (__hip_bfloat16*)(ws + off);

    __hip_bfloat16 *qkvWt[2], *projWt[2], *fc1Wt[2], *fc2Wt[2];
    size_t woff = 0;
    for (int d = 0; d < 2; ++d) { qkvWt[d] = wreg + woff; woff += 576 * 192; }
    for (int d = 0; d < 2; ++d) { projWt[d] = wreg + woff; woff += 192 * 192; }
    for (int d = 0; d < 2; ++d) { fc1Wt[d] = wreg + woff; woff += 768 * 192; }
    for (int d = 0; d < 2; ++d) { fc2Wt[d] = wreg + woff; woff += 192 * 768; }

    for (int d = 0; d < 2; ++d) {
        wcast_t<<<(192 * 576 + 255) / 256, 256, 0, stream>>>(qkv_w + (size_t)d * 192 * 576, qkvWt[d], 192, 576);
        wcast_t<<<(192 * 192 + 255) / 256, 256, 0, stream>>>(proj_w + (size_t)d * 192 * 192, projWt[d], 192, 192);
        wcast_t<<<(192 * 768 + 255) / 256, 256, 0, stream>>>(fc1_w + (size_t)d * 192 * 768, fc1Wt[d], 192, 768);
        wcast_t<<<(768 * 192 + 255) / 256, 256, 0, stream>>>(fc2_w + (size_t)d * 768 * 192, fc2Wt[d], 768, 192);
    }

    const int nrows = CB * 3136;
    for (int d = 0; d < 2; ++d) {
        int shift = d ? 3 : 0;
        const float* residA = d ? R : x;      // attention residual source
        const float* rpbd = rpb + (size_t)d * 169 * 6;

        // --- attention path (chunked over images) ---
        for (int b0 = 0; b0 < 64; b0 += CB) {
            ln_kernel<<<nrows / 4, 256, 0, stream>>>(residA, ln1_g + d * 192, ln1_b + d * 192,
                                                     bufA, b0, shift, 1);
            EpiParams e0 = {}; e0.out_bf = bufB; e0.ld = 576;
            gemm_bf16<0><<<dim3(nrows / 64, 9), 256, 0, stream>>>(bufA, qkvWt[d], qkv_b + d * 576, 192, e0);
            attn_kernel<<<dim3(CB * 64, 6), 64, 0, stream>>>(bufB, rpbd, bufA, shift);
            EpiParams e2 = {}; e2.out_f32 = R; e2.resid = residA; e2.b0 = b0; e2.shift = shift;
            gemm_bf16<2><<<dim3(nrows / 64, 3), 256, 0, stream>>>(bufA, projWt[d], proj_b + d * 192, 192, e2);
        }

        // --- MLP path (chunked over images) ---
        float* outF = d ? (float*)d_out : R;
        for (int b0 = 0; b0 < 64; b0 += CB) {
            ln_kernel<<<nrows / 4, 256, 0, stream>>>(R, ln2_g + d * 192, ln2_b + d * 192,
                                                     bufA, b0, 0, 0);
            EpiParams e1 = {}; e1.out_bf = bufB; e1.ld = 768;
            gemm_bf16<1><<<dim3(nrows / 64, 12), 256, 0, stream>>>(bufA, fc1Wt[d], fc1_b + d * 768, 192, e1);
            EpiParams e3 = {}; e3.out_f32 = outF; e3.resid = R; e3.b0 = b0;
            gemm_bf16<3><<<dim3(nrows / 64, 3), 256, 0, stream>>>(bufB, fc2Wt[d], fc2_b + d * 192, 768, e3);
        }
    }
}

// Round 2
// 2536.918 us; speedup vs baseline: 1.0796x; 1.0796x over previous
//
#include <hip/hip_runtime.h>
#include <hip/hip_bf16.h>
#include <math.h>

typedef __attribute__((ext_vector_type(8))) short short8;
typedef __attribute__((ext_vector_type(4))) float floatx4;
typedef __attribute__((ext_vector_type(4))) unsigned short ushort4v;

#define SCALE_F 0.17677669529663689f  // 1/sqrt(32)

__device__ __forceinline__ float bf2f(__hip_bfloat16 v){ return __bfloat162float(v); }

// async global->LDS 16B: per-lane global addr, wave-uniform LDS base + lane*16
__device__ __forceinline__ void gll16(const __hip_bfloat16* g, __hip_bfloat16* s) {
    __builtin_amdgcn_global_load_lds((const __attribute__((address_space(1))) unsigned int*)g,
                                     (__attribute__((address_space(3))) unsigned int*)s, 16, 0, 0);
}

// ---------------- weight cast + transpose: src fp32 (K x N) -> dst bf16 (N x K) ----------------
__global__ void wcast_t(const float* __restrict__ src, __hip_bfloat16* __restrict__ dst, int K, int N)
{
    int idx = blockIdx.x * 256 + threadIdx.x;
    if (idx >= K * N) return;
    int n = idx / K, k = idx - n * K;
    dst[idx] = __float2bfloat16(src[(size_t)k * N + n]);
}

// ---------------- LayerNorm (+ optional shift + window partition) -> bf16 rows ----------------
__global__ __launch_bounds__(256)
void ln_kernel(const float* __restrict__ x, const float* __restrict__ g,
               const float* __restrict__ bb, __hip_bfloat16* __restrict__ out,
               int b0, int shift, int windowed)
{
    int wave = threadIdx.x >> 6, lane = threadIdx.x & 63;
    int wr = blockIdx.x * 4 + wave;
    size_t src;
    if (windowed) {
        int win = wr / 49, t = wr - win * 49;
        int bl = win >> 6, wrem = win & 63;
        int wh = wrem >> 3, ww = wrem & 7;
        int i = t / 7, j = t - i * 7;
        int hh = wh * 7 + i + shift; if (hh >= 56) hh -= 56;
        int wp = ww * 7 + j + shift; if (wp >= 56) wp -= 56;
        src = (size_t)(b0 + bl) * 3136 + hh * 56 + wp;
    } else {
        src = (size_t)b0 * 3136 + wr;
    }
    const float* xr = x + src * 192;
    float v0 = xr[lane], v1 = xr[lane + 64], v2 = xr[lane + 128];
    float s = v0 + v1 + v2, ss = v0 * v0 + v1 * v1 + v2 * v2;
    #pragma unroll
    for (int o = 32; o; o >>= 1) { s += __shfl_xor(s, o); ss += __shfl_xor(ss, o); }
    float mu = s * (1.f / 192.f);
    float rs = rsqrtf(ss * (1.f / 192.f) - mu * mu + 1e-5f);
    __hip_bfloat16* op = out + (size_t)wr * 192;
    op[lane]       = __float2bfloat16((v0 - mu) * rs * g[lane]       + bb[lane]);
    op[lane + 64]  = __float2bfloat16((v1 - mu) * rs * g[lane + 64]  + bb[lane + 64]);
    op[lane + 128] = __float2bfloat16((v2 - mu) * rs * g[lane + 128] + bb[lane + 128]);
}

// ---------------- MFMA attention: one wave per (window, head), 49 padded to 64 ----------------
// qkv rows: (win*49+t, 576), col = which*192 + head*32 + d. out rows: (win*49+t, 192).
// S^T = K*Q^T via mfma (D[m][n]); softmax over m (regs + 2 shfl); P->LDS [n][m]; O = P*V.
__global__ __launch_bounds__(64)
void attn_mfma(const __hip_bfloat16* __restrict__ qkv, const float* __restrict__ rpb,
               __hip_bfloat16* __restrict__ out, int shift)
{
    __shared__ float rp_s[169];
    __shared__ __align__(16) unsigned short Ps[64 * 72];   // P[n][m] bf16, stride 72
    const int win = blockIdx.x, head = blockIdx.y;
    const int lane = threadIdx.x;
    const int q = lane >> 4, l = lane & 15;
    const __hip_bfloat16* base = qkv + (size_t)win * 49 * 576 + head * 32;

    for (int i = lane; i < 169; i += 64) rp_s[i] = rpb[i * 6 + head];

    // K A-frags (A[m=l][k=q*8+j]) and Q B-frags (B[k=q*8+j][n=l]) straight from global, row-clamped
    short8 kf[4], qf[4];
    #pragma unroll
    for (int t = 0; t < 4; ++t) {
        int m = t * 16 + l; int mc = m < 49 ? m : 48;
        kf[t] = *(const short8*)(base + (size_t)mc * 576 + 192 + q * 8);
        qf[t] = *(const short8*)(base + (size_t)mc * 576 + q * 8);
    }
    floatx4 st[4][4];
    #pragma unroll
    for (int mt = 0; mt < 4; ++mt)
        #pragma unroll
        for (int nt = 0; nt < 4; ++nt) {
            floatx4 z = {0.f, 0.f, 0.f, 0.f};
            st[mt][nt] = __builtin_amdgcn_mfma_f32_16x16x32_bf16(kf[mt], qf[nt], z, 0, 0, 0);
        }

    // V B-frags (B[k=m][j=d]): gather u16 from global, row-clamped (pads hit real finite data * P=0)
    short8 vb[2][2];
    #pragma unroll
    for (int mk = 0; mk < 2; ++mk)
        #pragma unroll
        for (int j = 0; j < 8; ++j) {
            int m = mk * 32 + q * 8 + j; int mc = m < 49 ? m : 48;
            const short* vp = (const short*)(base + (size_t)mc * 576 + 384 + l);
            vb[mk][0][j] = vp[0];
            vb[mk][1][j] = vp[16];
        }

    // per-lane m-side indices: m = 16*mt + 4*q + r
    const int wrem = win & 63, wh = wrem >> 3, ww = wrem & 7;
    const bool edgeH = (wh == 7), edgeW = (ww == 7);
    int mi[16], mj[16], idm[16]; bool mok[16];
    #pragma unroll
    for (int mt = 0; mt < 4; ++mt)
        #pragma unroll
        for (int r = 0; r < 4; ++r) {
            int ii = mt * 4 + r;
            int m = mt * 16 + q * 4 + r;
            int d7 = (m * 37) >> 8;           // m/7, exact for m<64
            mi[ii] = d7; mj[ii] = m - d7 * 7;
            mok[ii] = (m < 49);
            int ih = edgeH ? (d7 < 4 ? 1 : 2) : 0;
            int iw = edgeW ? ((m - d7 * 7) < 4 ? 1 : 2) : 0;
            idm[ii] = ih * 3 + iw;
        }
    __syncthreads();  // rp_s ready

    // softmax per n-column (n = 16*nt + l), write P tiles immediately (keeps regs low)
    #pragma unroll
    for (int nt = 0; nt < 4; ++nt) {
        int n = nt * 16 + l;
        int ri = (n * 37) >> 8; int rj = n - ri * 7;
        int ihn = edgeH ? (ri < 4 ? 1 : 2) : 0;
        int iwn = edgeW ? (rj < 4 ? 1 : 2) : 0;
        int idn = ihn * 3 + iwn;
        float sv[16];
        float mx = -3e38f;
        #pragma unroll
        for (int mt = 0; mt < 4; ++mt)
            #pragma unroll
            for (int r = 0; r < 4; ++r) {
                int ii = mt * 4 + r;
                float s = st[mt][nt][r] * SCALE_F + rp_s[(ri - mi[ii] + 6) * 13 + (rj - mj[ii] + 6)];
                if (shift > 0 && idm[ii] != idn) s -= 100.f;
                if (!mok[ii]) s = -3e38f;
                sv[ii] = s;
                mx = fmaxf(mx, s);
            }
        mx = fmaxf(mx, __shfl_xor(mx, 16));
        mx = fmaxf(mx, __shfl_xor(mx, 32));
        float sum = 0.f;
        #pragma unroll
        for (int ii = 0; ii < 16; ++ii) { float e = __expf(sv[ii] - mx); sv[ii] = e; sum += e; }
        sum += __shfl_xor(sum, 16);
        sum += __shfl_xor(sum, 32);
        float inv = 1.f / sum;
        #pragma unroll
        for (int mt = 0; mt < 4; ++mt) {
            ushort4v pk;
            #pragma unroll
            for (int r = 0; r < 4; ++r) {
                __hip_bfloat16 h = __float2bfloat16(sv[mt * 4 + r] * inv);
                pk[r] = *(unsigned short*)&h;
            }
            *(ushort4v*)(&Ps[(size_t)(nt * 16 + l) * 72 + mt * 16 + q * 4]) = pk;
        }
    }
    __syncthreads();  // P visible (drains LDS writes)

    // O = P*V : A-frag = P[n=l][m chunk] (b128 from LDS), B-frag = vb
    floatx4 o[4][2];
    #pragma unroll
    for (int nt = 0; nt < 4; ++nt)
        #pragma unroll
        for (int dt = 0; dt < 2; ++dt) o[nt][dt] = floatx4{0.f, 0.f, 0.f, 0.f};
    #pragma unroll
    for (int mk = 0; mk < 2; ++mk)
        #pragma unroll
        for (int nt = 0; nt < 4; ++nt) {
            short8 pf = *(const short8*)(&Ps[(size_t)(nt * 16 + l) * 72 + mk * 32 + q * 8]);
            #pragma unroll
            for (int dt = 0; dt < 2; ++dt)
                o[nt][dt] = __builtin_amdgcn_mfma_f32_16x16x32_bf16(pf, vb[mk][dt], o[nt][dt], 0, 0, 0);
        }
    // store: O[n = 16nt+4q+r][d = 16dt+l]
    #pragma unroll
    for (int nt = 0; nt < 4; ++nt)
        #pragma unroll
        for (int r = 0; r < 4; ++r) {
            int n = nt * 16 + q * 4 + r;
            if (n < 49) {
                __hip_bfloat16* op = out + ((size_t)win * 49 + n) * 192 + head * 32 + l;
                op[0]  = __float2bfloat16(o[nt][0][r]);
                op[16] = __float2bfloat16(o[nt][1][r]);
            }
        }
}

// ---------------- GEMM: C = A(M x K bf16) @ Wt(N x K bf16)^T + bias, 128x64 tile ----------------
struct EpiParams {
    float* out_f32;
    const float* resid;
    __hip_bfloat16* out_bf;
    int b0;
    int shift;
    int ld;
};

template<int EPI>
__global__ __launch_bounds__(256)
void gemm128(const __hip_bfloat16* __restrict__ A,
             const __hip_bfloat16* __restrict__ Wt,
             const float* __restrict__ bias,
             int K, int M, EpiParams ep)
{
    __shared__ __align__(16) __hip_bfloat16 As[128 * 32];
    __shared__ __align__(16) __hip_bfloat16 Bs[64 * 32];
    const int tid = threadIdx.x;
    const int wave = tid >> 6, lane = tid & 63;
    const int q = lane >> 4, l = lane & 15;
    const int row0 = blockIdx.x * 128;
    const int col0 = blockIdx.y * 64;

    floatx4 acc[2][4];
    #pragma unroll
    for (int rt = 0; rt < 2; ++rt)
        #pragma unroll
        for (int ct = 0; ct < 4; ++ct) acc[rt][ct] = floatx4{0.f, 0.f, 0.f, 0.f};

    // staging: chunk c -> LDS offset c*16B; row = c>>2, part = c&3 (contiguous per global_load_lds rule)
    int ra0 = row0 + (tid >> 2);        if (ra0 > M - 1) ra0 = M - 1;
    int ra1 = row0 + 64 + (tid >> 2);   if (ra1 > M - 1) ra1 = M - 1;
    const __hip_bfloat16* Ag0 = A + (size_t)ra0 * K + (tid & 3) * 8;
    const __hip_bfloat16* Ag1 = A + (size_t)ra1 * K + (tid & 3) * 8;
    const __hip_bfloat16* Bg  = Wt + (size_t)(col0 + (tid >> 2)) * K + (tid & 3) * 8;
    __hip_bfloat16* as0 = As + (size_t)(wave * 64) * 8;
    __hip_bfloat16* as1 = As + (size_t)(256 + wave * 64) * 8;
    __hip_bfloat16* bs0 = Bs + (size_t)(wave * 64) * 8;

    for (int k0 = 0; k0 < K; k0 += 32) {
        __syncthreads();
        gll16(Ag0 + k0, as0);
        gll16(Ag1 + k0, as1);
        gll16(Bg + k0, bs0);
        __syncthreads();
        short8 a0 = *(const short8*)(As + (wave * 32 + l) * 32 + q * 8);
        short8 a1 = *(const short8*)(As + (wave * 32 + 16 + l) * 32 + q * 8);
        short8 b0 = *(const short8*)(Bs + (l) * 32 + q * 8);
        short8 b1 = *(const short8*)(Bs + (16 + l) * 32 + q * 8);
        short8 b2 = *(const short8*)(Bs + (32 + l) * 32 + q * 8);
        short8 b3 = *(const short8*)(Bs + (48 + l) * 32 + q * 8);
        acc[0][0] = __builtin_amdgcn_mfma_f32_16x16x32_bf16(a0, b0, acc[0][0], 0, 0, 0);
        acc[0][1] = __builtin_amdgcn_mfma_f32_16x16x32_bf16(a0, b1, acc[0][1], 0, 0, 0);
        acc[0][2] = __builtin_amdgcn_mfma_f32_16x16x32_bf16(a0, b2, acc[0][2], 0, 0, 0);
        acc[0][3] = __builtin_amdgcn_mfma_f32_16x16x32_bf16(a0, b3, acc[0][3], 0, 0, 0);
        acc[1][0] = __builtin_amdgcn_mfma_f32_16x16x32_bf16(a1, b0, acc[1][0], 0, 0, 0);
        acc[1][1] = __builtin_amdgcn_mfma_f32_16x16x32_bf16(a1, b1, acc[1][1], 0, 0, 0);
        acc[1][2] = __builtin_amdgcn_mfma_f32_16x16x32_bf16(a1, b2, acc[1][2], 0, 0, 0);
        acc[1][3] = __builtin_amdgcn_mfma_f32_16x16x32_bf16(a1, b3, acc[1][3], 0, 0, 0);
    }

    #pragma unroll
    for (int ct = 0; ct < 4; ++ct) {
        int col = col0 + ct * 16 + l;
        float bz = bias[col];
        #pragma unroll
        for (int rt = 0; rt < 2; ++rt)
            #pragma unroll
            for (int rr = 0; rr < 4; ++rr) {
                int row = row0 + wave * 32 + rt * 16 + q * 4 + rr;
                if (row >= M) continue;
                float v = acc[rt][ct][rr] + bz;
                if constexpr (EPI == 0) {
                    ep.out_bf[(size_t)row * ep.ld + col] = __float2bfloat16(v);
                } else if constexpr (EPI == 1) {
                    float gl = 0.5f * v * (1.f + erff(v * 0.70710678118654752f));
                    ep.out_bf[(size_t)row * ep.ld + col] = __float2bfloat16(gl);
                } else if constexpr (EPI == 2) {
                    int win = row / 49, t = row - win * 49;
                    int bl = win >> 6, wrem = win & 63;
                    int wh = wrem >> 3, ww = wrem & 7;
                    int i = t / 7, j = t - i * 7;
                    int hh = wh * 7 + i + ep.shift; if (hh >= 56) hh -= 56;
                    int wp = ww * 7 + j + ep.shift; if (wp >= 56) wp -= 56;
                    size_t tok = (size_t)(ep.b0 + bl) * 3136 + hh * 56 + wp;
                    size_t o = tok * 192 + col;
                    ep.out_f32[o] = ep.resid[o] + v;
                } else { // EPI == 3
                    size_t tok = (size_t)ep.b0 * 3136 + row;
                    size_t o = tok * 192 + col;
                    ep.out_f32[o] = ep.resid[o] + v;
                }
            }
    }
}

extern "C" void kernel_launch(void* const* d_in, const int* in_sizes, int n_in,
                              void* d_out, int out_size, void* d_ws, size_t ws_size,
                              hipStream_t stream)
{
    const float* x      = (const float*)d_in[0];
    const float* ln1_g  = (const float*)d_in[1];
    const float* ln1_b  = (const float*)d_in[2];
    const float* qkv_w  = (const float*)d_in[3];
    const float* qkv_b  = (const float*)d_in[4];
    const float* rpb    = (const float*)d_in[5];
    const float* proj_w = (const float*)d_in[6];
    const float* proj_b = (const float*)d_in[7];
    const float* ln2_g  = (const float*)d_in[8];
    const float* ln2_b  = (const float*)d_in[9];
    const float* fc1_w  = (const float*)d_in[10];
    const float* fc1_b  = (const float*)d_in[11];
    const float* fc2_w  = (const float*)d_in[12];
    const float* fc2_b  = (const float*)d_in[13];

    char* ws = (char*)d_ws;
    const size_t RN = 200704ull;

    int CB = 64;
    auto need = [&](int cb) -> size_t {
        return RN * 192 * 4
             + (size_t)cb * 3136 * 192 * 2
             + (size_t)cb * 3136 * 768 * 2
             + 884736ull * 2 + 4096;
    };
    while (CB > 2 && need(CB) > ws_size) CB >>= 1;   // CB>=2 keeps nrows % 128 == 0

    float* R = (float*)ws;
    size_t off = RN * 192 * 4;
    __hip_bfloat16* bufA = (__hip_bfloat16*)(ws + off); off += (size_t)CB * 3136 * 192 * 2;
    __hip_bfloat16* bufB = (__hip_bfloat16*)(ws + off); off += (size_t)CB * 3136 * 768 * 2;
    __hip_bfloat16* wreg = (__hip_bfloat16*)(ws + off);

    __hip_bfloat16 *qkvWt[2], *projWt[2], *fc1Wt[2], *fc2Wt[2];
    size_t woff = 0;
    for (int d = 0; d < 2; ++d) { qkvWt[d] = wreg + woff; woff += 576 * 192; }
    for (int d = 0; d < 2; ++d) { projWt[d] = wreg + woff; woff += 192 * 192; }
    for (int d = 0; d < 2; ++d) { fc1Wt[d] = wreg + woff; woff += 768 * 192; }
    for (int d = 0; d < 2; ++d) { fc2Wt[d] = wreg + woff; woff += 192 * 768; }

    for (int d = 0; d < 2; ++d) {
        wcast_t<<<(192 * 576 + 255) / 256, 256, 0, stream>>>(qkv_w + (size_t)d * 192 * 576, qkvWt[d], 192, 576);
        wcast_t<<<(192 * 192 + 255) / 256, 256, 0, stream>>>(proj_w + (size_t)d * 192 * 192, projWt[d], 192, 192);
        wcast_t<<<(192 * 768 + 255) / 256, 256, 0, stream>>>(fc1_w + (size_t)d * 192 * 768, fc1Wt[d], 192, 768);
        wcast_t<<<(768 * 192 + 255) / 256, 256, 0, stream>>>(fc2_w + (size_t)d * 768 * 192, fc2Wt[d], 768, 192);
    }

    const int nrows = CB * 3136;
    const int gm = (nrows + 127) / 128;
    for (int d = 0; d < 2; ++d) {
        int shift = d ? 3 : 0;
        const float* residA = d ? R : x;
        const float* rpbd = rpb + (size_t)d * 169 * 6;

        for (int b0 = 0; b0 < 64; b0 += CB) {
            ln_kernel<<<nrows / 4, 256, 0, stream>>>(residA, ln1_g + d * 192, ln1_b + d * 192,
                                                     bufA, b0, shift, 1);
            EpiParams e0 = {}; e0.out_bf = bufB; e0.ld = 576;
            gemm128<0><<<dim3(gm, 9), 256, 0, stream>>>(bufA, qkvWt[d], qkv_b + d * 576, 192, nrows, e0);
            attn_mfma<<<dim3(CB * 64, 6), 64, 0, stream>>>(bufB, rpbd, bufA, shift);
            EpiParams e2 = {}; e2.out_f32 = R; e2.resid = residA; e2.b0 = b0; e2.shift = shift;
            gemm128<2><<<dim3(gm, 3), 256, 0, stream>>>(bufA, projWt[d], proj_b + d * 192, 192, nrows, e2);
        }

        float* outF = d ? (float*)d_out : R;
        for (int b0 = 0; b0 < 64; b0 += CB) {
            ln_kernel<<<nrows / 4, 256, 0, stream>>>(R, ln2_g + d * 192, ln2_b + d * 192,
                                                     bufA, b0, 0, 0);
            EpiParams e1 = {}; e1.out_bf = bufB; e1.ld = 768;
            gemm128<1><<<dim3(gm, 12), 256, 0, stream>>>(bufA, fc1Wt[d], fc1_b + d * 768, 192, nrows, e1);
            EpiParams e3 = {}; e3.out_f32 = outF; e3.resid = R; e3.b0 = b0;
            gemm128<3><<<dim3(gm, 3), 256, 0, stream>>>(bufB, fc2Wt[d], fc2_b + d * 192, 768, nrows, e3);
        }
    }
}

// Round 3
// 2078.727 us; speedup vs baseline: 1.3176x; 1.2204x over previous
//
#include <hip/hip_runtime.h>
#include <hip/hip_bf16.h>
#include <math.h>

typedef __attribute__((ext_vector_type(8))) short short8;
typedef __attribute__((ext_vector_type(4))) float floatx4;
typedef __attribute__((ext_vector_type(4))) unsigned short ushort4v;

#define SCALE_F 0.17677669529663689f  // 1/sqrt(32)

__device__ __forceinline__ float bf2f(__hip_bfloat16 v){ return __bfloat162float(v); }

// ---------------- weight cast + transpose: src fp32 (K x N) -> dst bf16 (N x K) ----------------
__global__ void wcast_t(const float* __restrict__ src, __hip_bfloat16* __restrict__ dst, int K, int N)
{
    int idx = blockIdx.x * 256 + threadIdx.x;
    if (idx >= K * N) return;
    int n = idx / K, k = idx - n * K;
    dst[idx] = __float2bfloat16(src[(size_t)k * N + n]);
}

// ---------------- LayerNorm (token order) -> bf16 rows ----------------
__global__ __launch_bounds__(256)
void ln_kernel(const float* __restrict__ x, const float* __restrict__ g,
               const float* __restrict__ bb, __hip_bfloat16* __restrict__ out, int b0)
{
    int wave = threadIdx.x >> 6, lane = threadIdx.x & 63;
    int wr = blockIdx.x * 4 + wave;
    const float* xr = x + ((size_t)b0 * 3136 + wr) * 192;
    float v0 = xr[lane], v1 = xr[lane + 64], v2 = xr[lane + 128];
    float s = v0 + v1 + v2, ss = v0 * v0 + v1 * v1 + v2 * v2;
    #pragma unroll
    for (int o = 32; o; o >>= 1) { s += __shfl_xor(s, o); ss += __shfl_xor(ss, o); }
    float mu = s * (1.f / 192.f);
    float rs = rsqrtf(ss * (1.f / 192.f) - mu * mu + 1e-5f);
    __hip_bfloat16* op = out + (size_t)wr * 192;
    op[lane]       = __float2bfloat16((v0 - mu) * rs * g[lane]       + bb[lane]);
    op[lane + 64]  = __float2bfloat16((v1 - mu) * rs * g[lane + 64]  + bb[lane + 64]);
    op[lane + 128] = __float2bfloat16((v2 - mu) * rs * g[lane + 128] + bb[lane + 128]);
}

// ---------------- MFMA attention: one wave per (window, head); token-order gather/scatter ----------------
__global__ __launch_bounds__(64)
void attn_mfma(const __hip_bfloat16* __restrict__ qkv, const float* __restrict__ rpb,
               __hip_bfloat16* __restrict__ out, int shift)
{
    __shared__ float rp_s[169];
    __shared__ __align__(16) unsigned short Ps[64 * 72];   // P[n][m] bf16, stride 72
    const int win = blockIdx.x, head = blockIdx.y;
    const int lane = threadIdx.x;
    const int q = lane >> 4, l = lane & 15;
    const int bl = win >> 6, wrem = win & 63;
    const int wh = wrem >> 3, ww = wrem & 7;
    const __hip_bfloat16* base = qkv + head * 32;

    for (int i = lane; i < 169; i += 64) rp_s[i] = rpb[i * 6 + head];

    auto tokof = [&](int m) -> int {
        int mi = (m * 37) >> 8; int mj = m - mi * 7;
        int hh = wh * 7 + mi + shift; if (hh >= 56) hh -= 56;
        int wp = ww * 7 + mj + shift; if (wp >= 56) wp -= 56;
        return bl * 3136 + hh * 56 + wp;
    };

    // K A-frags (A[m=l][k=q*8+j]) and Q B-frags (B[k=q*8+j][n=l]), row-clamped
    short8 kf[4], qf[4];
    #pragma unroll
    for (int t = 0; t < 4; ++t) {
        int m = t * 16 + l; int mc = m < 49 ? m : 48;
        int r = tokof(mc);
        kf[t] = *(const short8*)(base + (size_t)r * 576 + 192 + q * 8);
        qf[t] = *(const short8*)(base + (size_t)r * 576 + q * 8);
    }
    floatx4 st[4][4];
    #pragma unroll
    for (int mt = 0; mt < 4; ++mt)
        #pragma unroll
        for (int nt = 0; nt < 4; ++nt) {
            floatx4 z = {0.f, 0.f, 0.f, 0.f};
            st[mt][nt] = __builtin_amdgcn_mfma_f32_16x16x32_bf16(kf[mt], qf[nt], z, 0, 0, 0);
        }

    // V B-frags (B[k=m][j=d]): u16 gather, row-clamped
    short8 vb[2][2];
    #pragma unroll
    for (int mk = 0; mk < 2; ++mk)
        #pragma unroll
        for (int j = 0; j < 8; ++j) {
            int m = mk * 32 + q * 8 + j; int mc = m < 49 ? m : 48;
            int r = tokof(mc);
            const short* vp = (const short*)(base + (size_t)r * 576 + 384 + l);
            vb[mk][0][j] = vp[0];
            vb[mk][1][j] = vp[16];
        }

    const bool edgeH = (wh == 7), edgeW = (ww == 7);
    int mi[16], mj[16], idm[16]; bool mok[16];
    #pragma unroll
    for (int mt = 0; mt < 4; ++mt)
        #pragma unroll
        for (int r = 0; r < 4; ++r) {
            int ii = mt * 4 + r;
            int m = mt * 16 + q * 4 + r;
            int d7 = (m * 37) >> 8;
            mi[ii] = d7; mj[ii] = m - d7 * 7;
            mok[ii] = (m < 49);
            int ih = edgeH ? (d7 < 4 ? 1 : 2) : 0;
            int iw = edgeW ? ((m - d7 * 7) < 4 ? 1 : 2) : 0;
            idm[ii] = ih * 3 + iw;
        }
    __syncthreads();

    #pragma unroll
    for (int nt = 0; nt < 4; ++nt) {
        int n = nt * 16 + l;
        int ri = (n * 37) >> 8; int rj = n - ri * 7;
        int ihn = edgeH ? (ri < 4 ? 1 : 2) : 0;
        int iwn = edgeW ? (rj < 4 ? 1 : 2) : 0;
        int idn = ihn * 3 + iwn;
        float sv[16];
        float mx = -3e38f;
        #pragma unroll
        for (int mt = 0; mt < 4; ++mt)
            #pragma unroll
            for (int r = 0; r < 4; ++r) {
                int ii = mt * 4 + r;
                float s = st[mt][nt][r] * SCALE_F + rp_s[(ri - mi[ii] + 6) * 13 + (rj - mj[ii] + 6)];
                if (shift > 0 && idm[ii] != idn) s -= 100.f;
                if (!mok[ii]) s = -3e38f;
                sv[ii] = s;
                mx = fmaxf(mx, s);
            }
        mx = fmaxf(mx, __shfl_xor(mx, 16));
        mx = fmaxf(mx, __shfl_xor(mx, 32));
        float sum = 0.f;
        #pragma unroll
        for (int ii = 0; ii < 16; ++ii) { float e = __expf(sv[ii] - mx); sv[ii] = e; sum += e; }
        sum += __shfl_xor(sum, 16);
        sum += __shfl_xor(sum, 32);
        float inv = 1.f / sum;
        #pragma unroll
        for (int mt = 0; mt < 4; ++mt) {
            ushort4v pk;
            #pragma unroll
            for (int r = 0; r < 4; ++r) {
                __hip_bfloat16 h = __float2bfloat16(sv[mt * 4 + r] * inv);
                pk[r] = *(unsigned short*)&h;
            }
            *(ushort4v*)(&Ps[(size_t)(nt * 16 + l) * 72 + mt * 16 + q * 4]) = pk;
        }
    }
    __syncthreads();

    floatx4 o[4][2];
    #pragma unroll
    for (int nt = 0; nt < 4; ++nt)
        #pragma unroll
        for (int dt = 0; dt < 2; ++dt) o[nt][dt] = floatx4{0.f, 0.f, 0.f, 0.f};
    #pragma unroll
    for (int mk = 0; mk < 2; ++mk)
        #pragma unroll
        for (int nt = 0; nt < 4; ++nt) {
            short8 pf = *(const short8*)(&Ps[(size_t)(nt * 16 + l) * 72 + mk * 32 + q * 8]);
            #pragma unroll
            for (int dt = 0; dt < 2; ++dt)
                o[nt][dt] = __builtin_amdgcn_mfma_f32_16x16x32_bf16(pf, vb[mk][dt], o[nt][dt], 0, 0, 0);
        }
    #pragma unroll
    for (int nt = 0; nt < 4; ++nt)
        #pragma unroll
        for (int r = 0; r < 4; ++r) {
            int n = nt * 16 + q * 4 + r;
            if (n < 49) {
                int tn = tokof(n);
                __hip_bfloat16* op = out + (size_t)tn * 192 + head * 32 + l;
                op[0]  = __float2bfloat16(o[nt][0][r]);
                op[16] = __float2bfloat16(o[nt][1][r]);
            }
        }
}

// ======== shared GEMM pieces: A-tile (128 x 192) LDS-resident, padded stride 200 ========
#define AST 200

__device__ __forceinline__ void stage_a192(const __hip_bfloat16* Atile, __hip_bfloat16* As, int tid)
{
    #pragma unroll
    for (int i = 0; i < 12; ++i) {
        int c = i * 256 + tid;
        int row = (c * 2731) >> 16;   // c / 24
        int col = c - row * 24;
        uint4 v = *(const uint4*)(Atile + (size_t)c * 8);
        *(uint4*)(As + row * AST + col * 8) = v;
    }
}

__device__ __forceinline__ void stage_b192(const __hip_bfloat16* Btile, __hip_bfloat16* Bs, int tid)
{
    #pragma unroll
    for (int i = 0; i < 6; ++i) {
        int c = i * 256 + tid;
        int row = (c * 2731) >> 16;
        int col = c - row * 24;
        uint4 v = *(const uint4*)(Btile + (size_t)c * 8);
        *(uint4*)(Bs + row * AST + col * 8) = v;
    }
}

// ---------------- gemm_k192<EPI,NT>: K=192, all NT col-tiles in-block ----------------
// EPI 0: bias, bf16 store; EPI 1: bias + GELU, bf16 store
template<int EPI, int NT>
__global__ __launch_bounds__(256)
void gemm_k192(const __hip_bfloat16* __restrict__ A,
               const __hip_bfloat16* __restrict__ Wt,
               const float* __restrict__ bias,
               __hip_bfloat16* __restrict__ out, int ld)
{
    __shared__ __align__(16) __hip_bfloat16 As[128 * AST];
    __shared__ __align__(16) __hip_bfloat16 Bs[64 * AST];
    const int tid = threadIdx.x;
    const int wave = tid >> 6, lane = tid & 63;
    const int q = lane >> 4, l = lane & 15;
    const int row0 = blockIdx.x * 128;

    stage_a192(A + (size_t)row0 * 192, As, tid);

    for (int ct = 0; ct < NT; ++ct) {
        __syncthreads();
        stage_b192(Wt + (size_t)ct * 64 * 192, Bs, tid);
        __syncthreads();
        floatx4 acc[2][4];
        #pragma unroll
        for (int rt = 0; rt < 2; ++rt)
            #pragma unroll
            for (int c = 0; c < 4; ++c) acc[rt][c] = floatx4{0.f, 0.f, 0.f, 0.f};
        #pragma unroll
        for (int k = 0; k < 6; ++k) {
            short8 a0 = *(const short8*)(As + (wave * 32 + l) * AST + k * 32 + q * 8);
            short8 a1 = *(const short8*)(As + (wave * 32 + 16 + l) * AST + k * 32 + q * 8);
            #pragma unroll
            for (int c = 0; c < 4; ++c) {
                short8 bf = *(const short8*)(Bs + (c * 16 + l) * AST + k * 32 + q * 8);
                acc[0][c] = __builtin_amdgcn_mfma_f32_16x16x32_bf16(a0, bf, acc[0][c], 0, 0, 0);
                acc[1][c] = __builtin_amdgcn_mfma_f32_16x16x32_bf16(a1, bf, acc[1][c], 0, 0, 0);
            }
        }
        #pragma unroll
        for (int c = 0; c < 4; ++c) {
            int col = ct * 64 + c * 16 + l;
            float bz = bias[col];
            #pragma unroll
            for (int rt = 0; rt < 2; ++rt)
                #pragma unroll
                for (int rr = 0; rr < 4; ++rr) {
                    int row = row0 + wave * 32 + rt * 16 + q * 4 + rr;
                    float v = acc[rt][c][rr] + bz;
                    if constexpr (EPI == 1)
                        v = 0.5f * v * (1.f + erff(v * 0.70710678118654752f));
                    out[(size_t)row * ld + col] = __float2bfloat16(v);
                }
        }
    }
}

// ---------------- proj GEMM (K=192, N=192) + residual + fused LN2 ----------------
__global__ __launch_bounds__(256)
void gemm_proj_ln(const __hip_bfloat16* __restrict__ A,
                  const __hip_bfloat16* __restrict__ Wt,
                  const float* __restrict__ pb,
                  const float* __restrict__ g2, const float* __restrict__ b2,
                  const float* __restrict__ resid, float* __restrict__ Rout,
                  __hip_bfloat16* __restrict__ lnout, int b0)
{
    __shared__ __align__(16) __hip_bfloat16 As[128 * AST];
    __shared__ __align__(16) __hip_bfloat16 Bs[64 * AST];
    const int tid = threadIdx.x;
    const int wave = tid >> 6, lane = tid & 63;
    const int q = lane >> 4, l = lane & 15;
    const int row0 = blockIdx.x * 128;

    stage_a192(A + (size_t)row0 * 192, As, tid);

    floatx4 acc[2][12];
    #pragma unroll
    for (int rt = 0; rt < 2; ++rt)
        #pragma unroll
        for (int j = 0; j < 12; ++j) acc[rt][j] = floatx4{0.f, 0.f, 0.f, 0.f};

    for (int ct = 0; ct < 3; ++ct) {
        __syncthreads();
        stage_b192(Wt + (size_t)ct * 64 * 192, Bs, tid);
        __syncthreads();
        #pragma unroll
        for (int k = 0; k < 6; ++k) {
            short8 a0 = *(const short8*)(As + (wave * 32 + l) * AST + k * 32 + q * 8);
            short8 a1 = *(const short8*)(As + (wave * 32 + 16 + l) * AST + k * 32 + q * 8);
            #pragma unroll
            for (int c = 0; c < 4; ++c) {
                short8 bf = *(const short8*)(Bs + (c * 16 + l) * AST + k * 32 + q * 8);
                acc[0][ct * 4 + c] = __builtin_amdgcn_mfma_f32_16x16x32_bf16(a0, bf, acc[0][ct * 4 + c], 0, 0, 0);
                acc[1][ct * 4 + c] = __builtin_amdgcn_mfma_f32_16x16x32_bf16(a1, bf, acc[1][ct * 4 + c], 0, 0, 0);
            }
        }
    }

    float gj[12], bj[12], pbj[12];
    #pragma unroll
    for (int j = 0; j < 12; ++j) {
        int col = (j >> 2) * 64 + (j & 3) * 16 + l;
        gj[j] = g2[col]; bj[j] = b2[col]; pbj[j] = pb[col];
    }
    #pragma unroll
    for (int rt = 0; rt < 2; ++rt)
        #pragma unroll
        for (int rr = 0; rr < 4; ++rr) {
            int row = row0 + wave * 32 + rt * 16 + q * 4 + rr;
            size_t rb = ((size_t)b0 * 3136 + row) * 192;
            float y[12];
            float s = 0.f, ss = 0.f;
            #pragma unroll
            for (int j = 0; j < 12; ++j) {
                int col = (j >> 2) * 64 + (j & 3) * 16 + l;
                float v = acc[rt][j][rr] + pbj[j] + resid[rb + col];
                y[j] = v; s += v; ss += v * v;
                Rout[rb + col] = v;
            }
            s += __shfl_xor(s, 1); ss += __shfl_xor(ss, 1);
            s += __shfl_xor(s, 2); ss += __shfl_xor(ss, 2);
            s += __shfl_xor(s, 4); ss += __shfl_xor(ss, 4);
            s += __shfl_xor(s, 8); ss += __shfl_xor(ss, 8);
            float mu = s * (1.f / 192.f);
            float rs = rsqrtf(ss * (1.f / 192.f) - mu * mu + 1e-5f);
            #pragma unroll
            for (int j = 0; j < 12; ++j) {
                int col = (j >> 2) * 64 + (j & 3) * 16 + l;
                lnout[(size_t)row * 192 + col] = __float2bfloat16((y[j] - mu) * rs * gj[j] + bj[j]);
            }
        }
}

// ---------------- fc2 GEMM (K=768, N=192) + residual -> fp32 out ----------------
__global__ __launch_bounds__(256)
void gemm_fc2(const __hip_bfloat16* __restrict__ A,
              const __hip_bfloat16* __restrict__ Wt,
              const float* __restrict__ bias,
              const float* __restrict__ resid, float* __restrict__ out, int b0)
{
    __shared__ __align__(16) __hip_bfloat16 As[128 * AST];
    __shared__ __align__(16) __hip_bfloat16 Bs[64 * AST];
    const int tid = threadIdx.x;
    const int wave = tid >> 6, lane = tid & 63;
    const int q = lane >> 4, l = lane & 15;
    const int row0 = blockIdx.x * 128;

    floatx4 acc[2][12];
    #pragma unroll
    for (int rt = 0; rt < 2; ++rt)
        #pragma unroll
        for (int j = 0; j < 12; ++j) acc[rt][j] = floatx4{0.f, 0.f, 0.f, 0.f};

    for (int kc = 0; kc < 4; ++kc) {
        __syncthreads();
        #pragma unroll
        for (int i = 0; i < 12; ++i) {
            int c = i * 256 + tid;
            int row = (c * 2731) >> 16;
            int col = c - row * 24;
            uint4 v = *(const uint4*)(A + (size_t)(row0 + row) * 768 + kc * 192 + col * 8);
            *(uint4*)(As + row * AST + col * 8) = v;
        }
        for (int ct = 0; ct < 3; ++ct) {
            __syncthreads();
            #pragma unroll
            for (int i = 0; i < 6; ++i) {
                int c = i * 256 + tid;
                int row = (c * 2731) >> 16;
                int col = c - row * 24;
                uint4 v = *(const uint4*)(Wt + (size_t)(ct * 64 + row) * 768 + kc * 192 + col * 8);
                *(uint4*)(Bs + row * AST + col * 8) = v;
            }
            __syncthreads();
            #pragma unroll
            for (int k = 0; k < 6; ++k) {
                short8 a0 = *(const short8*)(As + (wave * 32 + l) * AST + k * 32 + q * 8);
                short8 a1 = *(const short8*)(As + (wave * 32 + 16 + l) * AST + k * 32 + q * 8);
                #pragma unroll
                for (int c = 0; c < 4; ++c) {
                    short8 bf = *(const short8*)(Bs + (c * 16 + l) * AST + k * 32 + q * 8);
                    acc[0][ct * 4 + c] = __builtin_amdgcn_mfma_f32_16x16x32_bf16(a0, bf, acc[0][ct * 4 + c], 0, 0, 0);
                    acc[1][ct * 4 + c] = __builtin_amdgcn_mfma_f32_16x16x32_bf16(a1, bf, acc[1][ct * 4 + c], 0, 0, 0);
                }
            }
        }
    }

    float bzj[12];
    #pragma unroll
    for (int j = 0; j < 12; ++j) {
        int col = (j >> 2) * 64 + (j & 3) * 16 + l;
        bzj[j] = bias[col];
    }
    #pragma unroll
    for (int rt = 0; rt < 2; ++rt)
        #pragma unroll
        for (int rr = 0; rr < 4; ++rr) {
            int row = row0 + wave * 32 + rt * 16 + q * 4 + rr;
            size_t rb = ((size_t)b0 * 3136 + row) * 192;
            #pragma unroll
            for (int j = 0; j < 12; ++j) {
                int col = (j >> 2) * 64 + (j & 3) * 16 + l;
                out[rb + col] = resid[rb + col] + acc[rt][j][rr] + bzj[j];
            }
        }
}

extern "C" void kernel_launch(void* const* d_in, const int* in_sizes, int n_in,
                              void* d_out, int out_size, void* d_ws, size_t ws_size,
                              hipStream_t stream)
{
    const float* x      = (const float*)d_in[0];
    const float* ln1_g  = (const float*)d_in[1];
    const float* ln1_b  = (const float*)d_in[2];
    const float* qkv_w  = (const float*)d_in[3];
    const float* qkv_b  = (const float*)d_in[4];
    const float* rpb    = (const float*)d_in[5];
    const float* proj_w = (const float*)d_in[6];
    const float* proj_b = (const float*)d_in[7];
    const float* ln2_g  = (const float*)d_in[8];
    const float* ln2_b  = (const float*)d_in[9];
    const float* fc1_w  = (const float*)d_in[10];
    const float* fc1_b  = (const float*)d_in[11];
    const float* fc2_w  = (const float*)d_in[12];
    const float* fc2_b  = (const float*)d_in[13];

    char* ws = (char*)d_ws;
    const size_t RN = 200704ull;

    int CB = 64;
    auto need = [&](int cb) -> size_t {
        return RN * 192 * 4                               // fp32 residual stream
             + (size_t)cb * 3136 * (192 + 768 + 192) * 2  // bufA + bufB + bufC (bf16)
             + 884736ull * 2 + 4096;
    };
    while (CB > 2 && need(CB) > ws_size) CB >>= 1;   // CB even => M % 128 == 0

    float* R = (float*)ws;
    size_t off = RN * 192 * 4;
    __hip_bfloat16* bufA = (__hip_bfloat16*)(ws + off); off += (size_t)CB * 3136 * 192 * 2;
    __hip_bfloat16* bufB = (__hip_bfloat16*)(ws + off); off += (size_t)CB * 3136 * 768 * 2;
    __hip_bfloat16* bufC = (__hip_bfloat16*)(ws + off); off += (size_t)CB * 3136 * 192 * 2;
    __hip_bfloat16* wreg = (__hip_bfloat16*)(ws + off);

    __hip_bfloat16 *qkvWt[2], *projWt[2], *fc1Wt[2], *fc2Wt[2];
    size_t woff = 0;
    for (int d = 0; d < 2; ++d) { qkvWt[d] = wreg + woff; woff += 576 * 192; }
    for (int d = 0; d < 2; ++d) { projWt[d] = wreg + woff; woff += 192 * 192; }
    for (int d = 0; d < 2; ++d) { fc1Wt[d] = wreg + woff; woff += 768 * 192; }
    for (int d = 0; d < 2; ++d) { fc2Wt[d] = wreg + woff; woff += 192 * 768; }

    for (int d = 0; d < 2; ++d) {
        wcast_t<<<(192 * 576 + 255) / 256, 256, 0, stream>>>(qkv_w + (size_t)d * 192 * 576, qkvWt[d], 192, 576);
        wcast_t<<<(192 * 192 + 255) / 256, 256, 0, stream>>>(proj_w + (size_t)d * 192 * 192, projWt[d], 192, 192);
        wcast_t<<<(192 * 768 + 255) / 256, 256, 0, stream>>>(fc1_w + (size_t)d * 192 * 768, fc1Wt[d], 192, 768);
        wcast_t<<<(768 * 192 + 255) / 256, 256, 0, stream>>>(fc2_w + (size_t)d * 768 * 192, fc2Wt[d], 768, 192);
    }

    const int nrows = CB * 3136;
    const int gm = nrows / 128;
    for (int d = 0; d < 2; ++d) {
        int shift = d ? 3 : 0;
        const float* residA = d ? R : x;
        const float* rpbd = rpb + (size_t)d * 169 * 6;
        float* outF = d ? (float*)d_out : R;

        for (int b0 = 0; b0 < 64; b0 += CB) {
            ln_kernel<<<nrows / 4, 256, 0, stream>>>(residA, ln1_g + d * 192, ln1_b + d * 192, bufA, b0);
            gemm_k192<0, 9><<<gm, 256, 0, stream>>>(bufA, qkvWt[d], qkv_b + d * 576, bufB, 576);
            attn_mfma<<<dim3(CB * 64, 6), 64, 0, stream>>>(bufB, rpbd, bufA, shift);
            gemm_proj_ln<<<gm, 256, 0, stream>>>(bufA, projWt[d], proj_b + d * 192,
                                                 ln2_g + d * 192, ln2_b + d * 192,
                                                 residA, R, bufC, b0);
            gemm_k192<1, 12><<<gm, 256, 0, stream>>>(bufC, fc1Wt[d], fc1_b + d * 768, bufB, 768);
            gemm_fc2<<<gm, 256, 0, stream>>>(bufB, fc2Wt[d], fc2_b + d * 192, R, outF, b0);
        }
    }
}